// Round 14
// baseline (933.293 us; speedup 1.0000x reference)
//
#include <hip/hip_runtime.h>
#include <stdint.h>

// Problem dims (fixed)
#define BB 64
#define TT 32
#define EE 512
#define HH 512
#define VV 32000
#define G4 2048
#define NRNN 16

typedef _Float16 f16x8 __attribute__((ext_vector_type(8)));
typedef float f32x4 __attribute__((ext_vector_type(4)));

__device__ __forceinline__ unsigned short f2h(float f) {
  return __builtin_bit_cast(unsigned short, (_Float16)f);   // RNE hw cvt
}
__device__ __forceinline__ void gload_lds16(const unsigned short* g, unsigned short* l) {
  __builtin_amdgcn_global_load_lds((const __attribute__((address_space(1))) void*)g,
                                   (__attribute__((address_space(3))) void*)l, 16, 0, 0);
}
__device__ __forceinline__ float sigm(float x) { return 1.f / (1.f + __expf(-x)); }
__device__ __forceinline__ float tanh_fast(float x) {
  return 1.f - 2.f / (__expf(2.f * x) + 1.f);   // stable at +-inf
}

// L2-executed atomic add-and-return (sc0 = return old, NO sc1 -> the RMW is
// performed at the LOCAL XCD L2, not the coherence point).  All participants
// are pinned to one XCD, so writers and readers meet at the same L2 either
// way (if sc0-atomics turn out to execute at the coherence point, both sides
// still meet there -> slow but never hangs).
__device__ __forceinline__ int l2_add(int* p, int v) {
  int old;
  asm volatile("global_atomic_add %0, %1, %2, off sc0\n\ts_waitcnt vmcnt(0)"
               : "=v"(old) : "v"(p), "v"(v) : "memory");
  return old;
}

// ---------------------------------------------------------------------------
// Kernel 1: Gpre(2112 x 2048) = [feat; emb[cap]] @ W_ih.T + (b_ih + b_hh) [fp32]
// (unchanged, verified r2-r13)
// ---------------------------------------------------------------------------
__global__ __launch_bounds__(256) void k_gemm_ih(const float* __restrict__ feat,
                                                 const int* __restrict__ cap,
                                                 const float* __restrict__ emb,
                                                 const float* __restrict__ Bw,
                                                 const float* __restrict__ bih,
                                                 const float* __restrict__ bhh,
                                                 float* __restrict__ C) {
  __shared__ float As[16][128];
  __shared__ float Bs[16][128];
  const int tid = threadIdx.x;
  const int bx = blockIdx.x & 15;   // n tile 0..15
  const int by = blockIdx.x >> 4;   // m tile 0..16
  const int m0 = by * 128, n0 = bx * 128;
  const int tx = tid & 15, ty = tid >> 4;

  float acc[8][8];
#pragma unroll
  for (int i = 0; i < 8; i++)
#pragma unroll
    for (int j = 0; j < 8; j++) acc[i][j] = 0.f;

  const int lr = tid >> 1;           // row-in-tile 0..127
  const int lk = (tid & 1) * 8;      // 0 or 8
  int arow = m0 + lr; if (arow > 2111) arow = 2111;  // clamp (store guarded)
  const float* Ap;
  if (arow < BB) {
    Ap = feat + (size_t)arow * EE + lk;
  } else {
    int idx = arow - BB;
    int t = idx >> 6, b = idx & 63;
    Ap = emb + (size_t)cap[b * TT + t] * EE + lk;
  }
  const int brow = n0 + lr;          // < 2048 always
  const float* Bp = Bw + (size_t)brow * EE + lk;

  for (int k0 = 0; k0 < EE; k0 += 16) {
    float4 a0 = *(const float4*)(Ap + k0);
    float4 a1 = *(const float4*)(Ap + k0 + 4);
    float4 b0 = *(const float4*)(Bp + k0);
    float4 b1 = *(const float4*)(Bp + k0 + 4);
    __syncthreads();
    As[lk + 0][lr] = a0.x; As[lk + 1][lr] = a0.y; As[lk + 2][lr] = a0.z; As[lk + 3][lr] = a0.w;
    As[lk + 4][lr] = a1.x; As[lk + 5][lr] = a1.y; As[lk + 6][lr] = a1.z; As[lk + 7][lr] = a1.w;
    Bs[lk + 0][lr] = b0.x; Bs[lk + 1][lr] = b0.y; Bs[lk + 2][lr] = b0.z; Bs[lk + 3][lr] = b0.w;
    Bs[lk + 4][lr] = b1.x; Bs[lk + 5][lr] = b1.y; Bs[lk + 6][lr] = b1.z; Bs[lk + 7][lr] = b1.w;
    __syncthreads();
#pragma unroll
    for (int k = 0; k < 16; k++) {
      float a[8], b[8];
      *(float4*)&a[0] = *(const float4*)&As[k][ty * 8];
      *(float4*)&a[4] = *(const float4*)&As[k][ty * 8 + 4];
      *(float4*)&b[0] = *(const float4*)&Bs[k][tx * 8];
      *(float4*)&b[4] = *(const float4*)&Bs[k][tx * 8 + 4];
#pragma unroll
      for (int i = 0; i < 8; i++)
#pragma unroll
        for (int j = 0; j < 8; j++) acc[i][j] += a[i] * b[j];
    }
  }

  float bs[8];
#pragma unroll
  for (int j = 0; j < 8; j++) {
    int n = n0 + tx * 8 + j;
    bs[j] = bih[n] + bhh[n];
  }
#pragma unroll
  for (int i = 0; i < 8; i++) {
    int m = m0 + ty * 8 + i;
    if (m < 2112) {
      float4 o0, o1;
      o0.x = acc[i][0] + bs[0]; o0.y = acc[i][1] + bs[1];
      o0.z = acc[i][2] + bs[2]; o0.w = acc[i][3] + bs[3];
      o1.x = acc[i][4] + bs[4]; o1.y = acc[i][5] + bs[5];
      o1.z = acc[i][6] + bs[6]; o1.w = acc[i][7] + bs[7];
      *(float4*)(C + (size_t)m * G4 + n0 + tx * 8) = o0;
      *(float4*)(C + (size_t)m * G4 + n0 + tx * 8 + 4) = o1;
    }
  }
}

// ---------------------------------------------------------------------------
// Symmetric intra-XCD barrier: every worker's wave 0 polls all 16 arr lines
// with L2-local atomic add-0; no aggregator, no done lines.
// ---------------------------------------------------------------------------
__device__ __forceinline__ void bar_wait_all(int* arr, int tid, int p) {
  if (tid < 64) {
    for (;;) {
      int v = (tid < NRNN) ? l2_add(&arr[tid * 32], 0) : p;
      if (__all(v >= p)) break;
      __builtin_amdgcn_s_sleep(2);
    }
  }
  __syncthreads();
}

// ---------------------------------------------------------------------------
// Kernel 2: LSTM recurrence on ONE XCD (r13 body, L2-local flags).
// Grid = 256 blocks x 512 thr with 128KB LDS -> 1 block/CU -> 32 blocks/XCD.
// Blocks on physical XCD0 (s_getreg XCC_ID) claim 16 slots via agent CAS;
// all others exit.  Slot owns u0 = slot*32 (128 W-rows fp16 in LDS,
// gate-interleaved: row r = wave*16 + gate*4 + du -> epilogue gathers
// i,f,g,o by in-wave __shfl).  h exchanged through XCD0's L2 with PLAIN
// stores/loads; step flags via l2_add (+1 per phase / add-0 poll).
// Gpre prefetched to regs before each barrier.  c state in registers.
// ---------------------------------------------------------------------------
__global__ __launch_bounds__(512) void k_rnn(const float* __restrict__ Gpre,
                                             const float* __restrict__ Whh,
                                             unsigned short* __restrict__ hseq,
                                             int* __restrict__ flags) {
  __shared__ __align__(16) unsigned short W_lds[128 * 512];   // 128 KB
  __shared__ int slot_sh;
  const int tid = threadIdx.x;

  if (tid == 0) {
    int xcc;
    asm volatile("s_getreg_b32 %0, hwreg(HW_REG_XCC_ID)" : "=s"(xcc));
    int slot = -1;
    if ((xcc & 7) == 0)
      slot = __hip_atomic_fetch_add(&flags[512], 1, __ATOMIC_RELAXED, __HIP_MEMORY_SCOPE_AGENT);
    slot_sh = slot;
  }
  __syncthreads();
  const int slot = slot_sh;
  if (slot < 0 || slot >= NRNN) return;

  const int l = tid & 63;
  const int w = tid >> 6;        // wave 0..7
  const int lr = l & 15;
  const int kc = l >> 4;         // 0..3
  const int d = l & 3;
  const int u0 = slot * 32;
  const int u = u0 + w * 4 + d;  // epilogue-owned u (lanes lr<4)
  int* arr = flags;              // arr[slot*32]

  // ---- stage W_hh (f32 -> fp16) into LDS, gate-interleaved + chunk swizzle ----
#pragma unroll
  for (int it = 0; it < 16; ++it) {
    int id = it * 512 + tid;     // 0..8191
    int r = id >> 6, c = id & 63;
    int wv = r >> 4, g = (r >> 2) & 3, du = r & 3;
    const float* src = Whh + (size_t)(g * 512 + u0 + wv * 4 + du) * HH + c * 8;
    float4 a = *(const float4*)src;
    float4 b = *(const float4*)(src + 4);
    __align__(16) unsigned short t8[8];
    t8[0] = f2h(a.x); t8[1] = f2h(a.y); t8[2] = f2h(a.z); t8[3] = f2h(a.w);
    t8[4] = f2h(b.x); t8[5] = f2h(b.y); t8[6] = f2h(b.z); t8[7] = f2h(b.w);
    *(int4*)&W_lds[r * 512 + ((c ^ (r & 7)) * 8)] = *(const int4*)t8;
  }

  // ---- prime step (h=c=0) ----
  float c_reg[16];
  if (lr < 4) {
#pragma unroll
    for (int mt = 0; mt < 4; ++mt)
#pragma unroll
      for (int j = 0; j < 4; ++j) {
        int sample = mt * 16 + kc * 4 + j;
        const float* gp = Gpre + (size_t)sample * G4;
        float gi = gp[u], gg = gp[1024 + u], go = gp[1536 + u];
        float cn = sigm(gi) * tanh_fast(gg);
        float hn = sigm(go) * tanh_fast(cn);
        c_reg[mt * 4 + j] = cn;
        hseq[(size_t)sample * HH + u] = f2h(hn);
      }
  }
  asm volatile("s_waitcnt vmcnt(0)" ::: "memory");
  __syncthreads();               // also covers W_lds staging
  if (tid == 0) l2_add(&arr[slot * 32], 1);   // phase 1 arrival

  // ---- prefetch Gpre gate values for step 1 (latency hides under barrier) ----
  float gpre[4][16];
  if (lr < 4) {
#pragma unroll
    for (int mt = 0; mt < 4; ++mt)
#pragma unroll
      for (int j = 0; j < 4; ++j) {
        int sample = mt * 16 + kc * 4 + j;
        const float* gp = Gpre + (size_t)(1 * 64 + sample) * G4;
        gpre[0][mt * 4 + j] = gp[u];
        gpre[1][mt * 4 + j] = gp[512 + u];
        gpre[2][mt * 4 + j] = gp[1024 + u];
        gpre[3][mt * 4 + j] = gp[1536 + u];
      }
  }
  bar_wait_all(arr, tid, 1);

  // ---- 32 recurrent steps ----
  for (int s = 1; s <= TT; ++s) {
    const unsigned short* hin = hseq + (size_t)(s - 1) * (BB * HH);
    unsigned short* hout = hseq + (size_t)s * (BB * HH);

    f32x4 acc[4];
#pragma unroll
    for (int mt = 0; mt < 4; ++mt) acc[mt] = (f32x4){0.f, 0.f, 0.f, 0.f};
    const int wrow = w * 16 + lr;
#pragma unroll
    for (int kk = 0; kk < 16; ++kk) {
      int4 wq = *(const int4*)&W_lds[wrow * 512 + (((kk * 4 + kc) ^ (lr & 7)) * 8)];
      f16x8 wf = __builtin_bit_cast(f16x8, wq);
#pragma unroll
      for (int mt = 0; mt < 4; ++mt) {
        uint4 hq = *(const uint4*)(hin + (size_t)(mt * 16 + lr) * HH + kk * 32 + kc * 8);
        // mfma(A=h, B=W): col(lane&15) = W-row (gate,du); row-field = sample
        acc[mt] = __builtin_amdgcn_mfma_f32_16x16x32_f16(
            __builtin_bit_cast(f16x8, hq), wf, acc[mt], 0, 0, 0);
      }
    }

    // epilogue: gather i,f,g,o in-wave; lanes lr<4 own (sample, u0+w*4+d)
#pragma unroll
    for (int mt = 0; mt < 4; ++mt)
#pragma unroll
      for (int j = 0; j < 4; ++j) {
        float v = acc[mt][j];
        float gi = __shfl(v, (kc << 4) + d);
        float gf = __shfl(v, (kc << 4) + 4 + d);
        float gg = __shfl(v, (kc << 4) + 8 + d);
        float go = __shfl(v, (kc << 4) + 12 + d);
        if (lr < 4) {
          int sample = mt * 16 + kc * 4 + j;
          gi += gpre[0][mt * 4 + j];
          gf += gpre[1][mt * 4 + j];
          gg += gpre[2][mt * 4 + j];
          go += gpre[3][mt * 4 + j];
          float cn = sigm(gf) * c_reg[mt * 4 + j] + sigm(gi) * tanh_fast(gg);
          float hn = sigm(go) * tanh_fast(cn);
          c_reg[mt * 4 + j] = cn;
          hout[(size_t)sample * HH + u] = f2h(hn);
        }
      }
    asm volatile("s_waitcnt vmcnt(0)" ::: "memory");
    __syncthreads();
    if (tid == 0) l2_add(&arr[slot * 32], 1);   // phase s+1 arrival

    if (s < TT) {
      // prefetch Gpre for step s+1 (overlaps barrier wait)
      if (lr < 4) {
#pragma unroll
        for (int mt = 0; mt < 4; ++mt)
#pragma unroll
          for (int j = 0; j < 4; ++j) {
            int sample = mt * 16 + kc * 4 + j;
            const float* gp = Gpre + (size_t)((s + 1) * 64 + sample) * G4;
            gpre[0][mt * 4 + j] = gp[u];
            gpre[1][mt * 4 + j] = gp[512 + u];
            gpre[2][mt * 4 + j] = gp[1024 + u];
            gpre[3][mt * 4 + j] = gp[1536 + u];
          }
      }
      bar_wait_all(arr, tid, s + 1);
    }
  }
  // dispatch-end L2 writeback publishes hseq to the next kernel (r2 precedent)
}

// ---------------------------------------------------------------------------
// Kernel 3: Out = hseq[1..32] @ W_out.T + b_out   [fp16 MFMA, f32 out]
// 250 blocks x 512 thr, one 128-col vocab slice each; W slice in REGISTERS
// (f32->f16 preload); per step stage hseq[s] (64KB) -> LDS via gload_lds
// (inverse-swizzled source), 64 MFMA/wave, float4 stores.  (r12/r13 body.)
// ---------------------------------------------------------------------------
__global__ __launch_bounds__(512) void k_gemm_out(const unsigned short* __restrict__ hseq,
                                                  const float* __restrict__ Wout,
                                                  const float* __restrict__ bout,
                                                  float* __restrict__ out) {
  __shared__ __align__(16) unsigned short As[BB * HH];   // 64 KB
  const int tid = threadIdx.x;
  const int l = tid & 63;
  const int w = tid >> 6;
  const int n00 = blockIdx.x * 128;
  const int bcol = w * 16 + (l >> 4) * 4;
  const float4 bo0 = *(const float4*)(bout + n00 + bcol);

  // preload W_out slice f32 -> f16 fragments in registers (once)
  const int vr0 = n00 + w * 16 + (l & 15);
  const int kb = (l >> 4) * 8;
  uint4 w0r[16];
#pragma unroll
  for (int kt = 0; kt < 16; ++kt) {
    const float* p = Wout + (size_t)vr0 * HH + kt * 32 + kb;
    float4 a = *(const float4*)p;
    float4 b = *(const float4*)(p + 4);
    __align__(16) unsigned short t8[8];
    t8[0] = f2h(a.x); t8[1] = f2h(a.y); t8[2] = f2h(a.z); t8[3] = f2h(a.w);
    t8[4] = f2h(b.x); t8[5] = f2h(b.y); t8[6] = f2h(b.z); t8[7] = f2h(b.w);
    w0r[kt] = *(const uint4*)t8;
  }

  for (int s = 1; s <= TT; ++s) {
    if (s > 1) __syncthreads();          // As reads of prev step done
    const unsigned short* hs = hseq + (size_t)s * (BB * HH);
#pragma unroll
    for (int it = 0; it < 8; ++it) {
      int ci = it * 512 + tid;           // 16B-chunk index 0..4095
      int row = ci >> 6, cd = ci & 63;
      gload_lds16(hs + (size_t)row * HH + (cd ^ (row & 7)) * 8, As + ci * 8);
    }
    asm volatile("s_waitcnt vmcnt(0)" ::: "memory");
    __syncthreads();

    f32x4 acc0[4];
#pragma unroll
    for (int m = 0; m < 4; ++m) acc0[m] = (f32x4){0.f, 0.f, 0.f, 0.f};
#pragma unroll
    for (int m = 0; m < 4; ++m) {
      int row = m * 16 + (l & 15);
#pragma unroll
      for (int kt = 0; kt < 16; ++kt) {
        int c = kt * 4 + (l >> 4);
        f16x8 af = *(const f16x8*)&As[row * HH + (c ^ (row & 7)) * 8];
        // mfma(W, h): W-rows -> row-field (out col); h-rows -> col (out row)
        acc0[m] = __builtin_amdgcn_mfma_f32_16x16x32_f16(
            __builtin_bit_cast(f16x8, w0r[kt]), af, acc0[m], 0, 0, 0);
      }
    }
#pragma unroll
    for (int m = 0; m < 4; ++m) {
      int b = m * 16 + (l & 15);
      float* orow = out + ((size_t)(b * TT + (s - 1))) * VV + n00 + bcol;
      float4 v;
      v.x = acc0[m][0] + bo0.x;
      v.y = acc0[m][1] + bo0.y;
      v.z = acc0[m][2] + bo0.z;
      v.w = acc0[m][3] + bo0.w;
      *(float4*)orow = v;
    }
  }
}

// ---------------------------------------------------------------------------
extern "C" void kernel_launch(void* const* d_in, const int* in_sizes, int n_in,
                              void* d_out, int out_size, void* d_ws, size_t ws_size,
                              hipStream_t stream) {
  const float* feat = (const float*)d_in[0];
  const int* cap = (const int*)d_in[1];
  // d_in[2] = seq_len (constant 32)
  const float* emb = (const float*)d_in[3];
  const float* Wih = (const float*)d_in[4];
  const float* Whh = (const float*)d_in[5];
  const float* bih = (const float*)d_in[6];
  const float* bhh = (const float*)d_in[7];
  const float* Wout = (const float*)d_in[8];
  const float* bout = (const float*)d_in[9];
  float* out = (float*)d_out;

  char* ws = (char*)d_ws;
  float* Gpre = (float*)ws;                                   // 17,301,504
  unsigned short* hseq = (unsigned short*)(ws + 17301504);    //  2,162,688 (33 x 64 x 512 fp16)
  int* flags = (int*)(ws + 19464192);                         //      8,192

  hipMemsetAsync(flags, 0, 8192, stream);
  k_gemm_ih<<<dim3(17 * 16), dim3(256), 0, stream>>>(feat, cap, emb, Wih, bih, bhh, Gpre);
  k_rnn<<<dim3(256), dim3(512), 0, stream>>>(Gpre, Whh, hseq, flags);
  k_gemm_out<<<dim3(250), dim3(512), 0, stream>>>(hseq, Wout, bout, out);
}

// Round 15
// 479.834 us; speedup vs baseline: 1.9450x; 1.9450x over previous
//
#include <hip/hip_runtime.h>
#include <stdint.h>

// Problem dims (fixed)
#define BB 64
#define TT 32
#define EE 512
#define HH 512
#define VV 32000
#define G4 2048

typedef _Float16 f16x8 __attribute__((ext_vector_type(8)));
typedef float f32x4 __attribute__((ext_vector_type(4)));

__device__ __forceinline__ unsigned short f2h(float f) {
  return __builtin_bit_cast(unsigned short, (_Float16)f);   // RNE hw cvt
}
__device__ __forceinline__ void gload_lds16(const unsigned short* g, unsigned short* l) {
  __builtin_amdgcn_global_load_lds((const __attribute__((address_space(1))) void*)g,
                                   (__attribute__((address_space(3))) void*)l, 16, 0, 0);
}
__device__ __forceinline__ float sigm(float x) { return 1.f / (1.f + __expf(-x)); }
__device__ __forceinline__ float tanh_fast(float x) {
  return 1.f - 2.f / (__expf(2.f * x) + 1.f);   // stable at +-inf
}

// ---------------------------------------------------------------------------
// Kernel 1: Gpre(2112 x 2048) = [feat; emb[cap]] @ W_ih.T + (b_ih + b_hh) [fp32]
// (verbatim, verified r2-r14)
// ---------------------------------------------------------------------------
__global__ __launch_bounds__(256) void k_gemm_ih(const float* __restrict__ feat,
                                                 const int* __restrict__ cap,
                                                 const float* __restrict__ emb,
                                                 const float* __restrict__ Bw,
                                                 const float* __restrict__ bih,
                                                 const float* __restrict__ bhh,
                                                 float* __restrict__ C) {
  __shared__ float As[16][128];
  __shared__ float Bs[16][128];
  const int tid = threadIdx.x;
  const int bx = blockIdx.x & 15;   // n tile 0..15
  const int by = blockIdx.x >> 4;   // m tile 0..16
  const int m0 = by * 128, n0 = bx * 128;
  const int tx = tid & 15, ty = tid >> 4;

  float acc[8][8];
#pragma unroll
  for (int i = 0; i < 8; i++)
#pragma unroll
    for (int j = 0; j < 8; j++) acc[i][j] = 0.f;

  const int lr = tid >> 1;           // row-in-tile 0..127
  const int lk = (tid & 1) * 8;      // 0 or 8
  int arow = m0 + lr; if (arow > 2111) arow = 2111;  // clamp (store guarded)
  const float* Ap;
  if (arow < BB) {
    Ap = feat + (size_t)arow * EE + lk;
  } else {
    int idx = arow - BB;
    int t = idx >> 6, b = idx & 63;
    Ap = emb + (size_t)cap[b * TT + t] * EE + lk;
  }
  const int brow = n0 + lr;          // < 2048 always
  const float* Bp = Bw + (size_t)brow * EE + lk;

  for (int k0 = 0; k0 < EE; k0 += 16) {
    float4 a0 = *(const float4*)(Ap + k0);
    float4 a1 = *(const float4*)(Ap + k0 + 4);
    float4 b0 = *(const float4*)(Bp + k0);
    float4 b1 = *(const float4*)(Bp + k0 + 4);
    __syncthreads();
    As[lk + 0][lr] = a0.x; As[lk + 1][lr] = a0.y; As[lk + 2][lr] = a0.z; As[lk + 3][lr] = a0.w;
    As[lk + 4][lr] = a1.x; As[lk + 5][lr] = a1.y; As[lk + 6][lr] = a1.z; As[lk + 7][lr] = a1.w;
    Bs[lk + 0][lr] = b0.x; Bs[lk + 1][lr] = b0.y; Bs[lk + 2][lr] = b0.z; Bs[lk + 3][lr] = b0.w;
    Bs[lk + 4][lr] = b1.x; Bs[lk + 5][lr] = b1.y; Bs[lk + 6][lr] = b1.z; Bs[lk + 7][lr] = b1.w;
    __syncthreads();
#pragma unroll
    for (int k = 0; k < 16; k++) {
      float a[8], b[8];
      *(float4*)&a[0] = *(const float4*)&As[k][ty * 8];
      *(float4*)&a[4] = *(const float4*)&As[k][ty * 8 + 4];
      *(float4*)&b[0] = *(const float4*)&Bs[k][tx * 8];
      *(float4*)&b[4] = *(const float4*)&Bs[k][tx * 8 + 4];
#pragma unroll
      for (int i = 0; i < 8; i++)
#pragma unroll
        for (int j = 0; j < 8; j++) acc[i][j] += a[i] * b[j];
    }
  }

  float bs[8];
#pragma unroll
  for (int j = 0; j < 8; j++) {
    int n = n0 + tx * 8 + j;
    bs[j] = bih[n] + bhh[n];
  }
#pragma unroll
  for (int i = 0; i < 8; i++) {
    int m = m0 + ty * 8 + i;
    if (m < 2112) {
      float4 o0, o1;
      o0.x = acc[i][0] + bs[0]; o0.y = acc[i][1] + bs[1];
      o0.z = acc[i][2] + bs[2]; o0.w = acc[i][3] + bs[3];
      o1.x = acc[i][4] + bs[4]; o1.y = acc[i][5] + bs[5];
      o1.z = acc[i][6] + bs[6]; o1.w = acc[i][7] + bs[7];
      *(float4*)(C + (size_t)m * G4 + n0 + tx * 8) = o0;
      *(float4*)(C + (size_t)m * G4 + n0 + tx * 8 + 4) = o1;
    }
  }
}

// ---------------------------------------------------------------------------
// Fence-free device barrier for 64 co-resident blocks (r6-proven, 7.9us/step).
// h WRITTEN with relaxed agent atomics (coherence point), READ with plain
// cached loads (reader never touches an hseq[s] line before this barrier).
// ---------------------------------------------------------------------------
__device__ __forceinline__ void gridbar_nf(int* flags, int id) {
  asm volatile("s_waitcnt vmcnt(0)" ::: "memory");
  __syncthreads();
  if (threadIdx.x == 0)
    __hip_atomic_store(&flags[blockIdx.x], id, __ATOMIC_RELAXED, __HIP_MEMORY_SCOPE_AGENT);
  if (threadIdx.x < 64) {
    while (__hip_atomic_load(&flags[threadIdx.x], __ATOMIC_RELAXED, __HIP_MEMORY_SCOPE_AGENT) < id)
      __builtin_amdgcn_s_sleep(1);
  }
  __syncthreads();
}

// ---------------------------------------------------------------------------
// Kernel 2: persistent LSTM recurrence (r6's proven 254us kernel, hall
// removed).  64 blocks x 512 thr (8 waves).  Block owns u0=bid*8 (8 u x 4
// gates = 32 W-rows, fp16 in 32KB LDS, 16B-chunk XOR swizzle).  Wave
// (nt=w&1, mt=w>>1): 16 fp16 MFMAs/step.  Gate combine via XOR-swizzled LDS
// gate_buf (8KB).  Epilogue: 1 (sample,du) update/thread, c in reg, h-pair
// packed u32 via shfl, agent-atomic stored to hseq[s][sample][u] (fp16
// layout hseq16[s*32768 + es*512 + u]).  Gpre prefetched pre-barrier.
// ---------------------------------------------------------------------------
__global__ __launch_bounds__(512) void k_rnn(const float* __restrict__ Gpre,
                                             const float* __restrict__ Whh,
                                             char* hseq_base,
                                             int* __restrict__ flags) {
  __shared__ __align__(16) unsigned short W_lds[32 * 512];  // fp16 bits, 32 KB
  __shared__ float gate_buf[2048];                          // 8 KB
  unsigned short* hseq16 = (unsigned short*)hseq_base;
  unsigned int* hseq32 = (unsigned int*)hseq_base;

  const int tid = threadIdx.x;
  const int bid = blockIdx.x;
  const int u0 = bid * 8;
  const int l = tid & 63;
  const int w = tid >> 6;          // wave 0..7
  const int lr = l & 15;
  const int kc = l >> 4;           // 0..3
  const int nt = w & 1;            // n-tile (W-row half)
  const int mt = w >> 1;           // m-tile (16-sample group)
  const int es = w * 8 + (l >> 3); // 0..63
  const int edu = l & 7;           // 0..7

  // ---- stage W_hh (f32 -> fp16) into LDS, swizzled ----
  {
    int row = tid >> 4;            // 0..31  (= g*8 + du)
    int sub = tid & 15;
    int g = row >> 3, du = row & 7;
    const float* srcp = Whh + (size_t)(g * 512 + u0 + du) * HH;
#pragma unroll
    for (int c0 = 0; c0 < 4; ++c0) {
      int c = sub * 4 + c0;        // 16B-chunk index 0..63 (8 f32 -> 8 fp16)
      float4 va = *(const float4*)(srcp + c * 8);
      float4 vb = *(const float4*)(srcp + c * 8 + 4);
      __align__(16) unsigned short t8[8];
      t8[0] = f2h(va.x); t8[1] = f2h(va.y); t8[2] = f2h(va.z); t8[3] = f2h(va.w);
      t8[4] = f2h(vb.x); t8[5] = f2h(vb.y); t8[6] = f2h(vb.z); t8[7] = f2h(vb.w);
      *(int4*)((char*)W_lds + row * 1024 + ((c ^ (row & 7)) * 16)) = *(const int4*)t8;
    }
  }

  // ---- prime step (h=c=0): elementwise from Gpre rows 0..63 ----
  float c_reg;
  {
    const float* gp = Gpre + (size_t)es * G4 + u0 + edu;
    float gi = gp[0], gg = gp[1024], go = gp[1536];
    float cn = sigm(gi) * tanh_fast(gg);
    float hn = sigm(go) * tanh_fast(cn);
    c_reg = cn;
    unsigned int hb = f2h(hn);
    unsigned int other = (unsigned int)__shfl_xor((int)hb, 1);
    if (!(l & 1))
      __hip_atomic_store(&hseq32[(size_t)es * 256 + bid * 4 + (edu >> 1)],
                         hb | (other << 16), __ATOMIC_RELAXED, __HIP_MEMORY_SCOPE_AGENT);
  }

  // ---- prefetch Gpre gate values for step 1 (drained by barrier vmcnt) ----
  float pre[4];
#pragma unroll
  for (int g = 0; g < 4; ++g)
    pre[g] = Gpre[((size_t)(1 * 64) + es) * G4 + g * 512 + u0 + edu];

  gridbar_nf(flags, 1);   // covers W staging (lds) + h0 stores

  // ---- 32 recurrent steps ----
  for (int s = 1; s <= TT; ++s) {
    const unsigned short* hin = hseq16 + (size_t)(s - 1) * BB * HH;

    // MFMA phase: acc[sample-row][W-row col] over K=512
    f32x4 acc = {0.f, 0.f, 0.f, 0.f};
    const unsigned short* hbase = hin + (size_t)(mt * 16 + lr) * HH + kc * 8;
    const int wrow = nt * 16 + lr;
    const char* wbase = (const char*)W_lds + wrow * 1024;
#pragma unroll
    for (int kk = 0; kk < 16; ++kk) {
      uint4 hq = *(const uint4*)(hbase + kk * 32);
      int4 wq = *(const int4*)(wbase + (((kk * 4 + kc) ^ (wrow & 7)) * 16));
      f16x8 hf = __builtin_bit_cast(f16x8, hq);
      f16x8 wf = __builtin_bit_cast(f16x8, wq);
      acc = __builtin_amdgcn_mfma_f32_16x16x32_f16(hf, wf, acc, 0, 0, 0);
    }

    // write gate partials to LDS (XOR-swizzled on sample index)
    {
      int g = nt * 2 + (lr >> 3);
      int du = lr & 7;
#pragma unroll
      for (int j = 0; j < 4; ++j) {
        int ss = mt * 16 + kc * 4 + j;
        gate_buf[g * 512 + du * 64 + (ss ^ (du << 3))] = acc[j];
      }
    }
    __syncthreads();

    // epilogue: one (es, edu) update per thread
    {
      float gi = gate_buf[0 * 512 + edu * 64 + (es ^ (edu << 3))] + pre[0];
      float gf = gate_buf[1 * 512 + edu * 64 + (es ^ (edu << 3))] + pre[1];
      float gg = gate_buf[2 * 512 + edu * 64 + (es ^ (edu << 3))] + pre[2];
      float go = gate_buf[3 * 512 + edu * 64 + (es ^ (edu << 3))] + pre[3];
      float cn = sigm(gf) * c_reg + sigm(gi) * tanh_fast(gg);
      float hn = sigm(go) * tanh_fast(cn);
      c_reg = cn;
      unsigned int hb = f2h(hn);
      unsigned int other = (unsigned int)__shfl_xor((int)hb, 1);
      if (!(l & 1))
        __hip_atomic_store(&hseq32[(size_t)s * 16384 + es * 256 + bid * 4 + (edu >> 1)],
                           hb | (other << 16), __ATOMIC_RELAXED, __HIP_MEMORY_SCOPE_AGENT);
    }

    if (s < TT) {
      // prefetch Gpre for step s+1 (overlaps barrier arrival/poll)
#pragma unroll
      for (int g = 0; g < 4; ++g)
        pre[g] = Gpre[((size_t)(s + 1) * 64 + es) * G4 + g * 512 + u0 + edu];
      gridbar_nf(flags, s + 1);
    }
  }
  // dispatch-end writeback publishes hseq to k_gemm_out (r12-r14 precedent)
}

// ---------------------------------------------------------------------------
// Kernel 3: Out = hseq[1..32] @ W_out.T + b_out   [fp16 MFMA, f32 out]
// (verbatim r12-r14, passed r13/r14).  250 blocks x 512 thr, one 128-col
// vocab slice each; W slice in REGISTERS (f32->f16 preload); per step stage
// hseq[s] (64KB) -> LDS via gload_lds (inverse-swizzled source), float4
// stores.
// ---------------------------------------------------------------------------
__global__ __launch_bounds__(512) void k_gemm_out(const unsigned short* __restrict__ hseq,
                                                  const float* __restrict__ Wout,
                                                  const float* __restrict__ bout,
                                                  float* __restrict__ out) {
  __shared__ __align__(16) unsigned short As[BB * HH];   // 64 KB
  const int tid = threadIdx.x;
  const int l = tid & 63;
  const int w = tid >> 6;
  const int n00 = blockIdx.x * 128;
  const int bcol = w * 16 + (l >> 4) * 4;
  const float4 bo0 = *(const float4*)(bout + n00 + bcol);

  // preload W_out slice f32 -> f16 fragments in registers (once)
  const int vr0 = n00 + w * 16 + (l & 15);
  const int kb = (l >> 4) * 8;
  uint4 w0r[16];
#pragma unroll
  for (int kt = 0; kt < 16; ++kt) {
    const float* p = Wout + (size_t)vr0 * HH + kt * 32 + kb;
    float4 a = *(const float4*)p;
    float4 b = *(const float4*)(p + 4);
    __align__(16) unsigned short t8[8];
    t8[0] = f2h(a.x); t8[1] = f2h(a.y); t8[2] = f2h(a.z); t8[3] = f2h(a.w);
    t8[4] = f2h(b.x); t8[5] = f2h(b.y); t8[6] = f2h(b.z); t8[7] = f2h(b.w);
    w0r[kt] = *(const uint4*)t8;
  }

  for (int s = 1; s <= TT; ++s) {
    if (s > 1) __syncthreads();          // As reads of prev step done
    const unsigned short* hs = hseq + (size_t)s * (BB * HH);
#pragma unroll
    for (int it = 0; it < 8; ++it) {
      int ci = it * 512 + tid;           // 16B-chunk index 0..4095
      int row = ci >> 6, cd = ci & 63;
      gload_lds16(hs + (size_t)row * HH + (cd ^ (row & 7)) * 8, As + ci * 8);
    }
    asm volatile("s_waitcnt vmcnt(0)" ::: "memory");
    __syncthreads();

    f32x4 acc0[4];
#pragma unroll
    for (int m = 0; m < 4; ++m) acc0[m] = (f32x4){0.f, 0.f, 0.f, 0.f};
#pragma unroll
    for (int m = 0; m < 4; ++m) {
      int row = m * 16 + (l & 15);
#pragma unroll
      for (int kt = 0; kt < 16; ++kt) {
        int c = kt * 4 + (l >> 4);
        f16x8 af = *(const f16x8*)&As[row * HH + (c ^ (row & 7)) * 8];
        // mfma(W, h): W-rows -> row-field (out col); h-rows -> col (out row)
        acc0[m] = __builtin_amdgcn_mfma_f32_16x16x32_f16(
            __builtin_bit_cast(f16x8, w0r[kt]), af, acc0[m], 0, 0, 0);
      }
    }
#pragma unroll
    for (int m = 0; m < 4; ++m) {
      int b = m * 16 + (l & 15);
      float* orow = out + ((size_t)(b * TT + (s - 1))) * VV + n00 + bcol;
      float4 v;
      v.x = acc0[m][0] + bo0.x;
      v.y = acc0[m][1] + bo0.y;
      v.z = acc0[m][2] + bo0.z;
      v.w = acc0[m][3] + bo0.w;
      *(float4*)orow = v;
    }
  }
}

// ---------------------------------------------------------------------------
extern "C" void kernel_launch(void* const* d_in, const int* in_sizes, int n_in,
                              void* d_out, int out_size, void* d_ws, size_t ws_size,
                              hipStream_t stream) {
  const float* feat = (const float*)d_in[0];
  const int* cap = (const int*)d_in[1];
  // d_in[2] = seq_len (constant 32)
  const float* emb = (const float*)d_in[3];
  const float* Wih = (const float*)d_in[4];
  const float* Whh = (const float*)d_in[5];
  const float* bih = (const float*)d_in[6];
  const float* bhh = (const float*)d_in[7];
  const float* Wout = (const float*)d_in[8];
  const float* bout = (const float*)d_in[9];
  float* out = (float*)d_out;

  char* ws = (char*)d_ws;
  float* Gpre = (float*)ws;                                   // 17,301,504
  char* hseq = ws + 17301504;                                 //  2,162,688 (33 x 64 x 512 fp16)
  int* flags = (int*)(ws + 19464192);                         //        256

  hipMemsetAsync(flags, 0, 4096, stream);
  k_gemm_ih<<<dim3(17 * 16), dim3(256), 0, stream>>>(feat, cap, emb, Wih, bih, bhh, Gpre);
  k_rnn<<<dim3(64), dim3(512), 0, stream>>>(Gpre, Whh, hseq, flags);
  k_gemm_out<<<dim3(250), dim3(512), 0, stream>>>((const unsigned short*)hseq, Wout, bout, out);
}

// Round 16
// 460.775 us; speedup vs baseline: 2.0255x; 1.0414x over previous
//
#include <hip/hip_runtime.h>
#include <stdint.h>

// Problem dims (fixed)
#define BB 64
#define TT 32
#define EE 512
#define HH 512
#define VV 32000
#define G4 2048

typedef _Float16 f16x8 __attribute__((ext_vector_type(8)));
typedef float f32x4 __attribute__((ext_vector_type(4)));

__device__ __forceinline__ unsigned short f2h(float f) {
  return __builtin_bit_cast(unsigned short, (_Float16)f);   // RNE hw cvt
}
__device__ __forceinline__ void gload_lds16(const unsigned short* g, unsigned short* l) {
  __builtin_amdgcn_global_load_lds((const __attribute__((address_space(1))) void*)g,
                                   (__attribute__((address_space(3))) void*)l, 16, 0, 0);
}
__device__ __forceinline__ float sigm(float x) { return 1.f / (1.f + __expf(-x)); }
__device__ __forceinline__ float tanh_fast(float x) {
  return 1.f - 2.f / (__expf(2.f * x) + 1.f);   // stable at +-inf
}

// ---------------------------------------------------------------------------
// Kernel 1: Gpre(2112 x 2048) = [feat; emb[cap]] @ W_ih.T + (b_ih + b_hh) [fp32]
// (verbatim, verified r2-r15)
// ---------------------------------------------------------------------------
__global__ __launch_bounds__(256) void k_gemm_ih(const float* __restrict__ feat,
                                                 const int* __restrict__ cap,
                                                 const float* __restrict__ emb,
                                                 const float* __restrict__ Bw,
                                                 const float* __restrict__ bih,
                                                 const float* __restrict__ bhh,
                                                 float* __restrict__ C) {
  __shared__ float As[16][128];
  __shared__ float Bs[16][128];
  const int tid = threadIdx.x;
  const int bx = blockIdx.x & 15;   // n tile 0..15
  const int by = blockIdx.x >> 4;   // m tile 0..16
  const int m0 = by * 128, n0 = bx * 128;
  const int tx = tid & 15, ty = tid >> 4;

  float acc[8][8];
#pragma unroll
  for (int i = 0; i < 8; i++)
#pragma unroll
    for (int j = 0; j < 8; j++) acc[i][j] = 0.f;

  const int lr = tid >> 1;           // row-in-tile 0..127
  const int lk = (tid & 1) * 8;      // 0 or 8
  int arow = m0 + lr; if (arow > 2111) arow = 2111;  // clamp (store guarded)
  const float* Ap;
  if (arow < BB) {
    Ap = feat + (size_t)arow * EE + lk;
  } else {
    int idx = arow - BB;
    int t = idx >> 6, b = idx & 63;
    Ap = emb + (size_t)cap[b * TT + t] * EE + lk;
  }
  const int brow = n0 + lr;          // < 2048 always
  const float* Bp = Bw + (size_t)brow * EE + lk;

  for (int k0 = 0; k0 < EE; k0 += 16) {
    float4 a0 = *(const float4*)(Ap + k0);
    float4 a1 = *(const float4*)(Ap + k0 + 4);
    float4 b0 = *(const float4*)(Bp + k0);
    float4 b1 = *(const float4*)(Bp + k0 + 4);
    __syncthreads();
    As[lk + 0][lr] = a0.x; As[lk + 1][lr] = a0.y; As[lk + 2][lr] = a0.z; As[lk + 3][lr] = a0.w;
    As[lk + 4][lr] = a1.x; As[lk + 5][lr] = a1.y; As[lk + 6][lr] = a1.z; As[lk + 7][lr] = a1.w;
    Bs[lk + 0][lr] = b0.x; Bs[lk + 1][lr] = b0.y; Bs[lk + 2][lr] = b0.z; Bs[lk + 3][lr] = b0.w;
    Bs[lk + 4][lr] = b1.x; Bs[lk + 5][lr] = b1.y; Bs[lk + 6][lr] = b1.z; Bs[lk + 7][lr] = b1.w;
    __syncthreads();
#pragma unroll
    for (int k = 0; k < 16; k++) {
      float a[8], b[8];
      *(float4*)&a[0] = *(const float4*)&As[k][ty * 8];
      *(float4*)&a[4] = *(const float4*)&As[k][ty * 8 + 4];
      *(float4*)&b[0] = *(const float4*)&Bs[k][tx * 8];
      *(float4*)&b[4] = *(const float4*)&Bs[k][tx * 8 + 4];
#pragma unroll
      for (int i = 0; i < 8; i++)
#pragma unroll
        for (int j = 0; j < 8; j++) acc[i][j] += a[i] * b[j];
    }
  }

  float bs[8];
#pragma unroll
  for (int j = 0; j < 8; j++) {
    int n = n0 + tx * 8 + j;
    bs[j] = bih[n] + bhh[n];
  }
#pragma unroll
  for (int i = 0; i < 8; i++) {
    int m = m0 + ty * 8 + i;
    if (m < 2112) {
      float4 o0, o1;
      o0.x = acc[i][0] + bs[0]; o0.y = acc[i][1] + bs[1];
      o0.z = acc[i][2] + bs[2]; o0.w = acc[i][3] + bs[3];
      o1.x = acc[i][4] + bs[4]; o1.y = acc[i][5] + bs[5];
      o1.z = acc[i][6] + bs[6]; o1.w = acc[i][7] + bs[7];
      *(float4*)(C + (size_t)m * G4 + n0 + tx * 8) = o0;
      *(float4*)(C + (size_t)m * G4 + n0 + tx * 8 + 4) = o1;
    }
  }
}

// ---------------------------------------------------------------------------
// Fence-free device barrier for 64 co-resident blocks (r6/r15-proven).
// h WRITTEN with relaxed agent atomics (coherence point), READ with plain
// cached loads.  Poll sleep 1 -> 4: lower CP fan-in pressure (4096 pollers).
// ---------------------------------------------------------------------------
__device__ __forceinline__ void gridbar_nf(int* flags, int id) {
  asm volatile("s_waitcnt vmcnt(0)" ::: "memory");
  __syncthreads();
  if (threadIdx.x == 0)
    __hip_atomic_store(&flags[blockIdx.x], id, __ATOMIC_RELAXED, __HIP_MEMORY_SCOPE_AGENT);
  if (threadIdx.x < 64) {
    while (__hip_atomic_load(&flags[threadIdx.x], __ATOMIC_RELAXED, __HIP_MEMORY_SCOPE_AGENT) < id)
      __builtin_amdgcn_s_sleep(4);
  }
  __syncthreads();
}

// ---------------------------------------------------------------------------
// Kernel 2: persistent LSTM recurrence (r6/r15-proven body, verbatim).
// 64 blocks x 512 thr (8 waves).  Block owns u0=bid*8; W_hh fp16 in 32KB
// LDS (16B-chunk XOR swizzle); 16 fp16 MFMAs/wave/step; gate combine via
// XOR-swizzled gate_buf; c in reg; h packed-u32 agent-atomic to hseq[s];
// Gpre prefetched pre-barrier.
// ---------------------------------------------------------------------------
__global__ __launch_bounds__(512) void k_rnn(const float* __restrict__ Gpre,
                                             const float* __restrict__ Whh,
                                             char* hseq_base,
                                             int* __restrict__ flags) {
  __shared__ __align__(16) unsigned short W_lds[32 * 512];  // fp16 bits, 32 KB
  __shared__ float gate_buf[2048];                          // 8 KB
  unsigned short* hseq16 = (unsigned short*)hseq_base;
  unsigned int* hseq32 = (unsigned int*)hseq_base;

  const int tid = threadIdx.x;
  const int bid = blockIdx.x;
  const int u0 = bid * 8;
  const int l = tid & 63;
  const int w = tid >> 6;          // wave 0..7
  const int lr = l & 15;
  const int kc = l >> 4;           // 0..3
  const int nt = w & 1;            // n-tile (W-row half)
  const int mt = w >> 1;           // m-tile (16-sample group)
  const int es = w * 8 + (l >> 3); // 0..63
  const int edu = l & 7;           // 0..7

  // ---- stage W_hh (f32 -> fp16) into LDS, swizzled ----
  {
    int row = tid >> 4;            // 0..31  (= g*8 + du)
    int sub = tid & 15;
    int g = row >> 3, du = row & 7;
    const float* srcp = Whh + (size_t)(g * 512 + u0 + du) * HH;
#pragma unroll
    for (int c0 = 0; c0 < 4; ++c0) {
      int c = sub * 4 + c0;        // 16B-chunk index 0..63 (8 f32 -> 8 fp16)
      float4 va = *(const float4*)(srcp + c * 8);
      float4 vb = *(const float4*)(srcp + c * 8 + 4);
      __align__(16) unsigned short t8[8];
      t8[0] = f2h(va.x); t8[1] = f2h(va.y); t8[2] = f2h(va.z); t8[3] = f2h(va.w);
      t8[4] = f2h(vb.x); t8[5] = f2h(vb.y); t8[6] = f2h(vb.z); t8[7] = f2h(vb.w);
      *(int4*)((char*)W_lds + row * 1024 + ((c ^ (row & 7)) * 16)) = *(const int4*)t8;
    }
  }

  // ---- prime step (h=c=0): elementwise from Gpre rows 0..63 ----
  float c_reg;
  {
    const float* gp = Gpre + (size_t)es * G4 + u0 + edu;
    float gi = gp[0], gg = gp[1024], go = gp[1536];
    float cn = sigm(gi) * tanh_fast(gg);
    float hn = sigm(go) * tanh_fast(cn);
    c_reg = cn;
    unsigned int hb = f2h(hn);
    unsigned int other = (unsigned int)__shfl_xor((int)hb, 1);
    if (!(l & 1))
      __hip_atomic_store(&hseq32[(size_t)es * 256 + bid * 4 + (edu >> 1)],
                         hb | (other << 16), __ATOMIC_RELAXED, __HIP_MEMORY_SCOPE_AGENT);
  }

  // ---- prefetch Gpre gate values for step 1 (drained by barrier vmcnt) ----
  float pre[4];
#pragma unroll
  for (int g = 0; g < 4; ++g)
    pre[g] = Gpre[((size_t)(1 * 64) + es) * G4 + g * 512 + u0 + edu];

  gridbar_nf(flags, 1);   // covers W staging (lds) + h0 stores

  // ---- 32 recurrent steps ----
  for (int s = 1; s <= TT; ++s) {
    const unsigned short* hin = hseq16 + (size_t)(s - 1) * BB * HH;

    // MFMA phase: acc[sample-row][W-row col] over K=512
    f32x4 acc = {0.f, 0.f, 0.f, 0.f};
    const unsigned short* hbase = hin + (size_t)(mt * 16 + lr) * HH + kc * 8;
    const int wrow = nt * 16 + lr;
    const char* wbase = (const char*)W_lds + wrow * 1024;
#pragma unroll
    for (int kk = 0; kk < 16; ++kk) {
      uint4 hq = *(const uint4*)(hbase + kk * 32);
      int4 wq = *(const int4*)(wbase + (((kk * 4 + kc) ^ (wrow & 7)) * 16));
      f16x8 hf = __builtin_bit_cast(f16x8, hq);
      f16x8 wf = __builtin_bit_cast(f16x8, wq);
      acc = __builtin_amdgcn_mfma_f32_16x16x32_f16(hf, wf, acc, 0, 0, 0);
    }

    // write gate partials to LDS (XOR-swizzled on sample index)
    {
      int g = nt * 2 + (lr >> 3);
      int du = lr & 7;
#pragma unroll
      for (int j = 0; j < 4; ++j) {
        int ss = mt * 16 + kc * 4 + j;
        gate_buf[g * 512 + du * 64 + (ss ^ (du << 3))] = acc[j];
      }
    }
    __syncthreads();

    // epilogue: one (es, edu) update per thread
    {
      float gi = gate_buf[0 * 512 + edu * 64 + (es ^ (edu << 3))] + pre[0];
      float gf = gate_buf[1 * 512 + edu * 64 + (es ^ (edu << 3))] + pre[1];
      float gg = gate_buf[2 * 512 + edu * 64 + (es ^ (edu << 3))] + pre[2];
      float go = gate_buf[3 * 512 + edu * 64 + (es ^ (edu << 3))] + pre[3];
      float cn = sigm(gf) * c_reg + sigm(gi) * tanh_fast(gg);
      float hn = sigm(go) * tanh_fast(cn);
      c_reg = cn;
      unsigned int hb = f2h(hn);
      unsigned int other = (unsigned int)__shfl_xor((int)hb, 1);
      if (!(l & 1))
        __hip_atomic_store(&hseq32[(size_t)s * 16384 + es * 256 + bid * 4 + (edu >> 1)],
                           hb | (other << 16), __ATOMIC_RELAXED, __HIP_MEMORY_SCOPE_AGENT);
    }

    if (s < TT) {
      // prefetch Gpre for step s+1 (overlaps barrier arrival/poll)
#pragma unroll
      for (int g = 0; g < 4; ++g)
        pre[g] = Gpre[((size_t)(s + 1) * 64 + es) * G4 + g * 512 + u0 + edu];
      gridbar_nf(flags, s + 1);
    }
  }
  // dispatch-end writeback publishes hseq to k_gemm_out (r12-r15 precedent)
}

// ---------------------------------------------------------------------------
// Kernel 3: Out = hseq[1..32] @ W_out.T + b_out   [fp16 MFMA, f32 out]
// 250 blocks x 512 thr, one 128-col vocab slice each; W slice in REGISTERS.
// NEW: DOUBLE-BUFFERED h staging (2 x 64KB LDS) — stage hseq[s+1] via
// gload_lds while computing step s; one vmcnt(0)+barrier per iteration
// orders {stage-done for cur} and {reads done before next overwrite}.
// ---------------------------------------------------------------------------
__global__ __launch_bounds__(512) void k_gemm_out(const unsigned short* __restrict__ hseq,
                                                  const float* __restrict__ Wout,
                                                  const float* __restrict__ bout,
                                                  float* __restrict__ out) {
  __shared__ __align__(16) unsigned short As[2][BB * HH];   // 2 x 64 KB
  const int tid = threadIdx.x;
  const int l = tid & 63;
  const int w = tid >> 6;
  const int n00 = blockIdx.x * 128;
  const int bcol = w * 16 + (l >> 4) * 4;
  const float4 bo0 = *(const float4*)(bout + n00 + bcol);

  // preload W_out slice f32 -> f16 fragments in registers (once)
  const int vr0 = n00 + w * 16 + (l & 15);
  const int kb = (l >> 4) * 8;
  uint4 w0r[16];
#pragma unroll
  for (int kt = 0; kt < 16; ++kt) {
    const float* p = Wout + (size_t)vr0 * HH + kt * 32 + kb;
    float4 a = *(const float4*)p;
    float4 b = *(const float4*)(p + 4);
    __align__(16) unsigned short t8[8];
    t8[0] = f2h(a.x); t8[1] = f2h(a.y); t8[2] = f2h(a.z); t8[3] = f2h(a.w);
    t8[4] = f2h(b.x); t8[5] = f2h(b.y); t8[6] = f2h(b.z); t8[7] = f2h(b.w);
    w0r[kt] = *(const uint4*)t8;
  }

  // staging task: thread covers 8 16B-chunks; inverse-swizzled source
  const unsigned short* hs1 = hseq + (size_t)1 * (BB * HH);
#pragma unroll
  for (int it = 0; it < 8; ++it) {
    int ci = it * 512 + tid;
    int row = ci >> 6, cd = ci & 63;
    gload_lds16(hs1 + (size_t)row * HH + (cd ^ (row & 7)) * 8, As[0] + ci * 8);
  }

  int cur = 0;
  for (int s = 1; s <= TT; ++s) {
    asm volatile("s_waitcnt vmcnt(0)" ::: "memory");   // stage of As[cur] done
    __syncthreads();                                   // + prev reads of As[cur] done

    if (s < TT) {
      const unsigned short* hs = hseq + (size_t)(s + 1) * (BB * HH);
#pragma unroll
      for (int it = 0; it < 8; ++it) {
        int ci = it * 512 + tid;
        int row = ci >> 6, cd = ci & 63;
        gload_lds16(hs + (size_t)row * HH + (cd ^ (row & 7)) * 8, As[cur ^ 1] + ci * 8);
      }
    }

    const unsigned short* Ab = As[cur];
    f32x4 acc0[4];
#pragma unroll
    for (int m = 0; m < 4; ++m) acc0[m] = (f32x4){0.f, 0.f, 0.f, 0.f};
#pragma unroll
    for (int m = 0; m < 4; ++m) {
      int row = m * 16 + (l & 15);
#pragma unroll
      for (int kt = 0; kt < 16; ++kt) {
        int c = kt * 4 + (l >> 4);
        f16x8 af = *(const f16x8*)&Ab[row * HH + (c ^ (row & 7)) * 8];
        // mfma(W, h): W-rows -> row-field (out col); h-rows -> col (out row)
        acc0[m] = __builtin_amdgcn_mfma_f32_16x16x32_f16(
            __builtin_bit_cast(f16x8, w0r[kt]), af, acc0[m], 0, 0, 0);
      }
    }
#pragma unroll
    for (int m = 0; m < 4; ++m) {
      int b = m * 16 + (l & 15);
      float* orow = out + ((size_t)(b * TT + (s - 1))) * VV + n00 + bcol;
      float4 v;
      v.x = acc0[m][0] + bo0.x;
      v.y = acc0[m][1] + bo0.y;
      v.z = acc0[m][2] + bo0.z;
      v.w = acc0[m][3] + bo0.w;
      *(float4*)orow = v;
    }
    cur ^= 1;
  }
}

// ---------------------------------------------------------------------------
extern "C" void kernel_launch(void* const* d_in, const int* in_sizes, int n_in,
                              void* d_out, int out_size, void* d_ws, size_t ws_size,
                              hipStream_t stream) {
  const float* feat = (const float*)d_in[0];
  const int* cap = (const int*)d_in[1];
  // d_in[2] = seq_len (constant 32)
  const float* emb = (const float*)d_in[3];
  const float* Wih = (const float*)d_in[4];
  const float* Whh = (const float*)d_in[5];
  const float* bih = (const float*)d_in[6];
  const float* bhh = (const float*)d_in[7];
  const float* Wout = (const float*)d_in[8];
  const float* bout = (const float*)d_in[9];
  float* out = (float*)d_out;

  char* ws = (char*)d_ws;
  float* Gpre = (float*)ws;                                   // 17,301,504
  char* hseq = ws + 17301504;                                 //  2,162,688 (33 x 64 x 512 fp16)
  int* flags = (int*)(ws + 19464192);                         //        256

  hipMemsetAsync(flags, 0, 4096, stream);
  k_gemm_ih<<<dim3(17 * 16), dim3(256), 0, stream>>>(feat, cap, emb, Wih, bih, bhh, Gpre);
  k_rnn<<<dim3(64), dim3(512), 0, stream>>>(Gpre, Whh, hseq, flags);
  k_gemm_out<<<dim3(250), dim3(512), 0, stream>>>((const unsigned short*)hseq, Wout, bout, out);
}